// Round 17
// baseline (430.024 us; speedup 1.0000x reference)
//
#include <hip/hip_runtime.h>

#define NN   100000
#define NE   1600000
#define DD   64
#define LL   4
#define GG   512
#define OUTC 10
#define EPSV 1e-5f
#define PART  391      // dst-partition size; 256 partitions (391*256 >= NN)
#define CAP   8192     // staging capacity per partition (mean 6250, +24 sigma)

// workspace layout (float offsets). Total 14,631,088 floats = 58.5 MB.
#define OFF_RS    0          // int rs[NN+1]
#define OFF_CSR   100016     // int csr_src[NE]; scan temp 'loc' overlays (dead before place)
#define OFF_BUFA  1700016    // bf16 t ping (first half) + bf16 v (second half)
#define OFF_BUFB  8100016    // bf16 t pong; uint staging[256*CAP]=8MB overlays pre-layers
#define OFF_POOL  14500016   // float pooled[GG*LL*DD]; deg int[NN] + bucketCnt[256] overlay

static __device__ __forceinline__ unsigned short f2bf(float f) {
    unsigned int u = __float_as_uint(f);
    unsigned int r = (u + 0x7fffu + ((u >> 16) & 1u)) >> 16;   // RNE, finite inputs
    return (unsigned short)r;
}
static __device__ __forceinline__ float plo(unsigned int v) {
    return __uint_as_float(v << 16);
}
static __device__ __forceinline__ float phi(unsigned int v) {
    return __uint_as_float(v & 0xffff0000u);
}

// ---- CSR build phase 1: single sweep, 256-way dst bucket ----
__global__ __launch_bounds__(256)
void bucket_kernel(const int* __restrict__ src, const int* __restrict__ dst,
                   int* __restrict__ bucketCnt, unsigned int* __restrict__ staging) {
    __shared__ int hist[256];
    __shared__ int base[256];
    int tid = threadIdx.x;
    hist[tid] = 0;
    __syncthreads();
    int e0 = blockIdx.x * 1024 + tid * 4;
    int b0 = 0, b1 = 0, b2 = 0, b3 = 0, p0 = 0, p1 = 0, p2 = 0, p3 = 0;
    unsigned int k0 = 0, k1 = 0, k2 = 0, k3 = 0;
    bool ok = (e0 < NE);                    // NE%4==0 -> tail int4-exact
    if (ok) {
        int4 d4 = *(const int4*)&dst[e0];
        int4 s4 = *(const int4*)&src[e0];
        b0 = d4.x / PART; k0 = ((unsigned int)(d4.x - b0 * PART) << 17) | (unsigned int)s4.x;
        b1 = d4.y / PART; k1 = ((unsigned int)(d4.y - b1 * PART) << 17) | (unsigned int)s4.y;
        b2 = d4.z / PART; k2 = ((unsigned int)(d4.z - b2 * PART) << 17) | (unsigned int)s4.z;
        b3 = d4.w / PART; k3 = ((unsigned int)(d4.w - b3 * PART) << 17) | (unsigned int)s4.w;
        p0 = atomicAdd(&hist[b0], 1);
        p1 = atomicAdd(&hist[b1], 1);
        p2 = atomicAdd(&hist[b2], 1);
        p3 = atomicAdd(&hist[b3], 1);
    }
    __syncthreads();
    base[tid] = atomicAdd(&bucketCnt[tid], hist[tid]);
    __syncthreads();
    if (ok) {
        staging[b0 * CAP + base[b0] + p0] = k0;
        staging[b1 * CAP + base[b1] + p1] = k1;
        staging[b2 * CAP + base[b2] + p2] = k2;
        staging[b3 * CAP + base[b3] + p3] = k3;
    }
}

// ---- Phase 2: degree count. Block b sweeps ONLY its ~6250-entry bucket.
__global__ __launch_bounds__(256)
void count_kernel(const unsigned int* __restrict__ staging,
                  const int* __restrict__ bucketCnt, int* __restrict__ deg) {
    __shared__ int hist[PART];
    int b = blockIdx.x;
    int tid = threadIdx.x;
    for (int i = tid; i < PART; i += 256) hist[i] = 0;
    __syncthreads();
    int cnt = bucketCnt[b];
    const unsigned int* st = staging + b * CAP;
    for (int i = tid; i < cnt; i += 256) atomicAdd(&hist[st[i] >> 17], 1);
    __syncthreads();
    int dbase = b * PART;
    for (int i = tid; i < PART; i += 256)
        if (dbase + i < NN) deg[dbase + i] = hist[i];
}

__global__ void scan1_kernel(const int* __restrict__ deg, int* __restrict__ loc,
                             int* __restrict__ bsum) {
    int t = threadIdx.x;
    int i = blockIdx.x * 1024 + t;
    int v = (i < NN) ? deg[i] : 0;
    __shared__ int ps[1024];
    ps[t] = v;
    __syncthreads();
    #pragma unroll
    for (int off = 1; off < 1024; off <<= 1) {
        int u = (t >= off) ? ps[t - off] : 0;
        __syncthreads();
        ps[t] += u;
        __syncthreads();
    }
    if (i < NN) loc[i] = ps[t] - v;
    if (t == 1023) bsum[blockIdx.x] = ps[1023];
}

__global__ void scan2_kernel(const int* __restrict__ bsum, int* __restrict__ boff) {
    int t = threadIdx.x;                      // 128 threads, 98 valid
    int v = (t < 98) ? bsum[t] : 0;
    __shared__ int ps[128];
    ps[t] = v;
    __syncthreads();
    #pragma unroll
    for (int off = 1; off < 128; off <<= 1) {
        int u = (t >= off) ? ps[t - off] : 0;
        __syncthreads();
        ps[t] += u;
        __syncthreads();
    }
    if (t < 98) boff[t] = ps[t] - v;
    if (t == 127) boff[98] = ps[127];
}

__global__ void scan3_kernel(const int* __restrict__ loc, const int* __restrict__ boff,
                             int* __restrict__ rs) {
    int i = blockIdx.x * 1024 + threadIdx.x;
    if (i < NN) rs[i] = loc[i] + boff[i >> 10];
    if (i == NN) rs[NN] = boff[98];
}

// ---- Phase 3: CSR place. Block b sweeps only its own bucket; single-writer csr region.
__global__ __launch_bounds__(256)
void place_kernel(const unsigned int* __restrict__ staging,
                  const int* __restrict__ bucketCnt, const int* __restrict__ rs,
                  int* __restrict__ csr) {
    __shared__ int cnt[PART];
    int b = blockIdx.x;
    int tid = threadIdx.x;
    for (int i = tid; i < PART; i += 256) cnt[i] = 0;
    __syncthreads();
    int n = bucketCnt[b];
    const unsigned int* st = staging + b * CAP;
    int dbase = b * PART;
    for (int i = tid; i < n; i += 256) {
        unsigned int v = st[i];
        int dloc = (int)(v >> 17);
        int slot = rs[dbase + dloc] + atomicAdd(&cnt[dloc], 1);
        csr[slot] = (int)(v & 0x1FFFFu);
    }
}

// t0 = bf16(x * deg^{-1/2}); last 16 blocks zero pooled (its overlay tenants
// deg/bucketCnt ARE dead here). sums is NOT zeroed here — it lives inside
// tping, which layer 1 overwrites (round-16 bug); it is memset just before mlp1.
__global__ void t0_kernel(const float* __restrict__ x, const int* __restrict__ rs,
                          unsigned short* __restrict__ t0, float* __restrict__ pooled) {
    int nb = gridDim.x - 16;
    if ((int)blockIdx.x >= nb) {
        int z = (blockIdx.x - nb) * 256 + threadIdx.x;   // 4096 threads
        #pragma unroll
        for (int i = 0; i < 32; ++i) pooled[z + i * 4096] = 0.f;  // 131072 floats
        return;
    }
    int i = blockIdx.x * 256 + threadIdx.x;   // over NN*16 quads
    int n = i >> 4;
    float di = rsqrtf((float)(rs[n + 1] - rs[n]) + 1.0f);
    float4 v = ((const float4*)x)[i];
    ushort4 o;
    o.x = f2bf(v.x * di); o.y = f2bf(v.y * di);
    o.z = f2bf(v.z * di); o.w = f2bf(v.w * di);
    ((ushort4*)t0)[i] = o;
}

// Gather ONLY: v[n] = bf16( dis[n] * (t[n] + sum_nbr t[src]) ).
// Quarter-wave per node; 16 rows in flight per quarter-wave (latency-vs-BW probe).
__global__ __launch_bounds__(256)
void gather_kernel(const unsigned short* __restrict__ t, const int* __restrict__ csr,
                   const int* __restrict__ rs, unsigned short* __restrict__ vout) {
    const uint2* tu2 = (const uint2*)t;
    uint2* vo2 = (uint2*)vout;
    int tid = threadIdx.x;
    // bijective XCD chunk-swizzle
    int nwg = gridDim.x;                 // 6250
    int q = nwg >> 3, r = nwg & 7;       // 781, 2
    int xcd = blockIdx.x & 7, sub = blockIdx.x >> 3;
    int bid = (xcd < r ? xcd * (q + 1) : r * (q + 1) + (xcd - r) * q) + sub;

    int n = bid * 16 + (tid >> 4);       // quarter-wave -> node
    int l = tid & 15;                    // uint2 index: channels 4l..4l+3
    int j0 = rs[n], j1 = rs[n + 1];
    float di = rsqrtf((float)(j1 - j0) + 1.0f);

    uint2 sv = tu2[n * 16 + l];          // self row
    float a0 = plo(sv.x), a1 = phi(sv.x), a2 = plo(sv.y), a3 = phi(sv.y);

    int j = j0;
    #pragma clang loop unroll(disable)
    for (; j + 15 < j1; j += 16) {       // 16 rows in flight per quarter
        int i0 = csr[j],      i1 = csr[j + 1],  i2 = csr[j + 2],  i3 = csr[j + 3];
        int i4 = csr[j + 4],  i5 = csr[j + 5],  i6 = csr[j + 6],  i7 = csr[j + 7];
        int i8 = csr[j + 8],  i9 = csr[j + 9],  iA = csr[j + 10], iB = csr[j + 11];
        int iC = csr[j + 12], iD = csr[j + 13], iE = csr[j + 14], iF = csr[j + 15];
        uint2 v0 = tu2[i0 * 16 + l];
        uint2 v1 = tu2[i1 * 16 + l];
        uint2 v2 = tu2[i2 * 16 + l];
        uint2 v3 = tu2[i3 * 16 + l];
        uint2 v4 = tu2[i4 * 16 + l];
        uint2 v5 = tu2[i5 * 16 + l];
        uint2 v6 = tu2[i6 * 16 + l];
        uint2 v7 = tu2[i7 * 16 + l];
        uint2 v8 = tu2[i8 * 16 + l];
        uint2 v9 = tu2[i9 * 16 + l];
        uint2 vA = tu2[iA * 16 + l];
        uint2 vB = tu2[iB * 16 + l];
        uint2 vC = tu2[iC * 16 + l];
        uint2 vD = tu2[iD * 16 + l];
        uint2 vE = tu2[iE * 16 + l];
        uint2 vF = tu2[iF * 16 + l];
        a0 += (((plo(v0.x) + plo(v1.x)) + (plo(v2.x) + plo(v3.x)))
             + ((plo(v4.x) + plo(v5.x)) + (plo(v6.x) + plo(v7.x))))
            + (((plo(v8.x) + plo(v9.x)) + (plo(vA.x) + plo(vB.x)))
             + ((plo(vC.x) + plo(vD.x)) + (plo(vE.x) + plo(vF.x))));
        a1 += (((phi(v0.x) + phi(v1.x)) + (phi(v2.x) + phi(v3.x)))
             + ((phi(v4.x) + phi(v5.x)) + (phi(v6.x) + phi(v7.x))))
            + (((phi(v8.x) + phi(v9.x)) + (phi(vA.x) + phi(vB.x)))
             + ((phi(vC.x) + phi(vD.x)) + (phi(vE.x) + phi(vF.x))));
        a2 += (((plo(v0.y) + plo(v1.y)) + (plo(v2.y) + plo(v3.y)))
             + ((plo(v4.y) + plo(v5.y)) + (plo(v6.y) + plo(v7.y))))
            + (((plo(v8.y) + plo(v9.y)) + (plo(vA.y) + plo(vB.y)))
             + ((plo(vC.y) + plo(vD.y)) + (plo(vE.y) + plo(vF.y))));
        a3 += (((phi(v0.y) + phi(v1.y)) + (phi(v2.y) + phi(v3.y)))
             + ((phi(v4.y) + phi(v5.y)) + (phi(v6.y) + phi(v7.y))))
            + (((phi(v8.y) + phi(v9.y)) + (phi(vA.y) + phi(vB.y)))
             + ((phi(vC.y) + phi(vD.y)) + (phi(vE.y) + phi(vF.y))));
    }
    #pragma clang loop unroll(disable)
    for (; j + 3 < j1; j += 4) {
        int i0 = csr[j], i1 = csr[j + 1], i2 = csr[j + 2], i3 = csr[j + 3];
        uint2 v0 = tu2[i0 * 16 + l];
        uint2 v1 = tu2[i1 * 16 + l];
        uint2 v2 = tu2[i2 * 16 + l];
        uint2 v3 = tu2[i3 * 16 + l];
        a0 += (plo(v0.x) + plo(v1.x)) + (plo(v2.x) + plo(v3.x));
        a1 += (phi(v0.x) + phi(v1.x)) + (phi(v2.x) + phi(v3.x));
        a2 += (plo(v0.y) + plo(v1.y)) + (plo(v2.y) + plo(v3.y));
        a3 += (phi(v0.y) + phi(v1.y)) + (phi(v2.y) + phi(v3.y));
    }
    #pragma clang loop unroll(disable)
    for (; j < j1; ++j) {
        uint2 v0 = tu2[csr[j] * 16 + l];
        a0 += plo(v0.x); a1 += phi(v0.x);
        a2 += plo(v0.y); a3 += phi(v0.y);
    }
    uint2 o;
    o.x = (unsigned int)f2bf(a0 * di) | ((unsigned int)f2bf(a1 * di) << 16);
    o.y = (unsigned int)f2bf(a2 * di) | ((unsigned int)f2bf(a3 * di) << 16);
    vo2[n * 16 + l] = o;
}

// Persistent-W grid-stride GEMM + epilogue: h = v @ W + b; tout = bf16(dis*h);
// pooled[batch] += h with LDS cross-wave reduction.
__global__ __launch_bounds__(256)
void vgemm_kernel(const unsigned short* __restrict__ v, const float* __restrict__ W,
                  const float* __restrict__ bias, const int* __restrict__ rs,
                  const int* __restrict__ batch, unsigned short* __restrict__ tout,
                  float* __restrict__ pooled, int l, int last) {
    __shared__ float Wsh[64 * 64];
    __shared__ float hs[16][64];
    __shared__ float red[4][64];
    const uint2* vu2 = (const uint2*)v;
    int tid = threadIdx.x;
    #pragma unroll
    for (int i = 0; i < 16; ++i) Wsh[tid + i * 256] = W[tid + i * 256];  // once/block
    int w = tid >> 6, d = tid & 63;
    float bd = bias[d];

    for (int c = blockIdx.x; c < NN / 16; c += gridDim.x) {
        int n0 = c * 16;
        {
            int rr = tid >> 4, cc = tid & 15;    // one uint2/thread = 4 channels
            uint2 u = vu2[(n0 + rr) * 16 + cc];
            hs[rr][4 * cc]     = plo(u.x);
            hs[rr][4 * cc + 1] = phi(u.x);
            hs[rr][4 * cc + 2] = plo(u.y);
            hs[rr][4 * cc + 3] = phi(u.y);
        }
        __syncthreads();
        float a0 = 0.f, a1 = 0.f, a2 = 0.f, a3 = 0.f;
        #pragma unroll 2
        for (int k4 = 0; k4 < 16; ++k4) {        // 4 b128 + 4 b32 LDS per 16 FMA
            float4 h0 = *(const float4*)&hs[w * 4 + 0][k4 * 4];
            float4 h1 = *(const float4*)&hs[w * 4 + 1][k4 * 4];
            float4 h2 = *(const float4*)&hs[w * 4 + 2][k4 * 4];
            float4 h3 = *(const float4*)&hs[w * 4 + 3][k4 * 4];
            float w0 = Wsh[(k4 * 4 + 0) * 64 + d];
            float w1 = Wsh[(k4 * 4 + 1) * 64 + d];
            float w2 = Wsh[(k4 * 4 + 2) * 64 + d];
            float w3 = Wsh[(k4 * 4 + 3) * 64 + d];
            a0 = fmaf(h0.x, w0, a0); a0 = fmaf(h0.y, w1, a0);
            a0 = fmaf(h0.z, w2, a0); a0 = fmaf(h0.w, w3, a0);
            a1 = fmaf(h1.x, w0, a1); a1 = fmaf(h1.y, w1, a1);
            a1 = fmaf(h1.z, w2, a1); a1 = fmaf(h1.w, w3, a1);
            a2 = fmaf(h2.x, w0, a2); a2 = fmaf(h2.y, w1, a2);
            a2 = fmaf(h2.z, w2, a2); a2 = fmaf(h2.w, w3, a2);
            a3 = fmaf(h3.x, w0, a3); a3 = fmaf(h3.y, w1, a3);
            a3 = fmaf(h3.z, w2, a3); a3 = fmaf(h3.w, w3, a3);
        }
        float accs[4] = {a0, a1, a2, a3};
        if (!last) {
            #pragma unroll
            for (int s = 0; s < 4; ++s) {
                int n = n0 + w * 4 + s;
                float di = rsqrtf((float)(rs[n + 1] - rs[n]) + 1.0f);
                tout[n * 64 + d] = f2bf((accs[s] + bd) * di);
            }
        }
        int glo = batch[n0], ghi = batch[n0 + 15];
        if (glo == ghi) {                         // block-uniform branch
            red[w][d] = ((a0 + a1) + (a2 + a3)) + 4.0f * bd;
            __syncthreads();
            if (w == 0) {
                float tot = (red[0][d] + red[1][d]) + (red[2][d] + red[3][d]);
                atomicAdd(&pooled[glo * 256 + l * 64 + d], tot);
            }
        } else {
            #pragma unroll
            for (int s = 0; s < 4; ++s) {
                int n = n0 + w * 4 + s;
                atomicAdd(&pooled[batch[n] * 256 + l * 64 + d], accs[s] + bd);
            }
        }
        __syncthreads();                          // hs/red reuse barrier
    }
}

__global__ void mlp1_kernel(const float* __restrict__ pooled, const float* __restrict__ W1,
                            const float* __restrict__ b1, float* __restrict__ z1,
                            float* __restrict__ sums) {
    __shared__ float row[256];
    int g = blockIdx.x, d = threadIdx.x;   // 64 threads
    #pragma unroll
    for (int i = 0; i < 4; ++i) row[d + i * 64] = pooled[g * 256 + d + i * 64];
    __syncthreads();
    float acc = b1[d];
    #pragma unroll 8
    for (int k = 0; k < 256; ++k) acc = fmaf(row[k], W1[k * 64 + d], acc);
    z1[g * 64 + d] = acc;
    atomicAdd(&sums[d], acc);
    atomicAdd(&sums[64 + d], acc * acc);
}

__global__ void mlp2_kernel(const float* __restrict__ z1, const float* __restrict__ sums,
                            const float* __restrict__ gamma, const float* __restrict__ beta,
                            const float* __restrict__ W2, const float* __restrict__ b2,
                            float* __restrict__ out) {
    int g = blockIdx.x, d = threadIdx.x;   // 64 threads = 1 wave
    float mean = sums[d] * (1.0f / 512.0f);
    float var  = sums[64 + d] * (1.0f / 512.0f) - mean * mean;
    float z = (z1[g * 64 + d] - mean) * rsqrtf(var + EPSV) * gamma[d] + beta[d];
    z = fmaxf(z, 0.0f);
    #pragma unroll
    for (int o = 0; o < OUTC; ++o) {
        float v = z * W2[d * OUTC + o];
        #pragma unroll
        for (int s = 32; s; s >>= 1) v += __shfl_xor(v, s, 64);
        if (d == 0) out[g * OUTC + o] = v + b2[o];
    }
}

extern "C" void kernel_launch(void* const* d_in, const int* in_sizes, int n_in,
                              void* d_out, int out_size, void* d_ws, size_t ws_size,
                              hipStream_t stream) {
    (void)in_sizes; (void)n_in; (void)out_size; (void)ws_size;
    const float* x     = (const float*)d_in[0];
    const int*   ei    = (const int*)d_in[1];
    const int*   src   = ei;
    const int*   dst   = ei + NE;
    const int*   batch = (const int*)d_in[2];
    const float* Wc    = (const float*)d_in[3];
    const float* bc    = (const float*)d_in[4];
    const float* W1    = (const float*)d_in[5];
    const float* b1    = (const float*)d_in[6];
    const float* gamma = (const float*)d_in[7];
    const float* beta  = (const float*)d_in[8];
    const float* W2    = (const float*)d_in[9];
    const float* b2    = (const float*)d_in[10];
    float* out = (float*)d_out;
    float* ws  = (float*)d_ws;

    int*   rs        = (int*)(ws + OFF_RS);
    int*   csr       = (int*)(ws + OFF_CSR);
    int*   loc       = (int*)(ws + OFF_CSR);        // scan temp, dead before place
    unsigned short* tping = (unsigned short*)(ws + OFF_BUFA);
    unsigned short* vbuf  = tping + 6400000;        // second half of BUFA region
    unsigned short* tpong = (unsigned short*)(ws + OFF_BUFB);
    unsigned int* staging = (unsigned int*)(ws + OFF_BUFB);  // 8 MB, dead before layers
    float* pooled = ws + OFF_POOL;
    int*   deg       = (int*)(ws + OFF_POOL);       // dead before t0's pooled-zero
    int*   bucketCnt = (int*)(ws + OFF_POOL) + NN;  // 256 ints, same overlay
    int*   bsum   = (int*)(ws + OFF_BUFA);          // scan temps, dead before t0
    int*   boff   = (int*)(ws + OFF_BUFA) + 128;
    float* z1     = ws + OFF_BUFA;                  // overlay, dead only AFTER layers
    float* sums   = ws + OFF_BUFA + GG * DD;        // inside tping -> zero AFTER layers

    // --- build CSR: bucket (1 sweep, 256-way) -> own-bucket count -> scan -> place ---
    hipMemsetAsync(bucketCnt, 0, 256 * sizeof(int), stream);
    bucket_kernel<<<(NE + 1023) / 1024, 256, 0, stream>>>(src, dst, bucketCnt, staging);
    count_kernel<<<256, 256, 0, stream>>>(staging, bucketCnt, deg);
    scan1_kernel<<<98, 1024, 0, stream>>>(deg, loc, bsum);
    scan2_kernel<<<1, 128, 0, stream>>>(bsum, boff);
    scan3_kernel<<<99, 1024, 0, stream>>>(loc, boff, rs);
    place_kernel<<<256, 256, 0, stream>>>(staging, bucketCnt, rs, csr);

    // --- t0 = bf16(x * dis); fused pooled zeroing (deg/bucketCnt dead now) ---
    t0_kernel<<<NN * 16 / 256 + 16, 256, 0, stream>>>(x, rs, tping, pooled);

    // --- layers: gather (latency-light) then persistent-W GEMM ---
    unsigned short* tin = tping; unsigned short* tot = tpong;
    for (int l = 0; l < LL; ++l) {
        gather_kernel<<<NN / 16, 256, 0, stream>>>(tin, csr, rs, vbuf);
        vgemm_kernel<<<768, 256, 0, stream>>>(vbuf, Wc + l * 4096, bc + l * 64,
                                              rs, batch, tot, pooled,
                                              l, l == LL - 1);
        unsigned short* tmp = tin; tin = tot; tot = tmp;
    }

    // --- MLP head: sums zeroed HERE (after all tping writes — round-16 lesson) ---
    hipMemsetAsync(sums, 0, 128 * sizeof(float), stream);
    mlp1_kernel<<<GG, 64, 0, stream>>>(pooled, W1, b1, z1, sums);
    mlp2_kernel<<<GG, 64, 0, stream>>>(z1, sums, gamma, beta, W2, b2, out);
}

// Round 18
// 420.848 us; speedup vs baseline: 1.0218x; 1.0218x over previous
//
#include <hip/hip_runtime.h>

#define NN   100000
#define NE   1600000
#define DD   64
#define LL   4
#define GG   512
#define OUTC 10
#define EPSV 1e-5f
#define PART  391      // dst-partition size; 256 partitions (391*256 >= NN)
#define CAP   8192     // staging capacity per partition (mean 6250, +24 sigma)

// workspace layout (float offsets). Total 14,631,088 floats = 58.5 MB.
#define OFF_RS    0          // int rs[NN+1]
#define OFF_CSR   100016     // int csr_src[NE]; scan temp 'loc' overlays (dead before place)
#define OFF_BUFA  1700016    // bf16 t ping (first half) + bf16 v (second half)
#define OFF_BUFB  8100016    // bf16 t pong; uint staging[256*CAP]=8MB overlays pre-layers
#define OFF_POOL  14500016   // float pooled[GG*LL*DD]; deg int[NN] + bucketCnt[256] overlay

static __device__ __forceinline__ unsigned short f2bf(float f) {
    unsigned int u = __float_as_uint(f);
    unsigned int r = (u + 0x7fffu + ((u >> 16) & 1u)) >> 16;   // RNE, finite inputs
    return (unsigned short)r;
}
static __device__ __forceinline__ float plo(unsigned int v) {
    return __uint_as_float(v << 16);
}
static __device__ __forceinline__ float phi(unsigned int v) {
    return __uint_as_float(v & 0xffff0000u);
}

// ---- CSR build phase 1: single sweep, 256-way dst bucket ----
__global__ __launch_bounds__(256)
void bucket_kernel(const int* __restrict__ src, const int* __restrict__ dst,
                   int* __restrict__ bucketCnt, unsigned int* __restrict__ staging) {
    __shared__ int hist[256];
    __shared__ int base[256];
    int tid = threadIdx.x;
    hist[tid] = 0;
    __syncthreads();
    int e0 = blockIdx.x * 1024 + tid * 4;
    int b0 = 0, b1 = 0, b2 = 0, b3 = 0, p0 = 0, p1 = 0, p2 = 0, p3 = 0;
    unsigned int k0 = 0, k1 = 0, k2 = 0, k3 = 0;
    bool ok = (e0 < NE);                    // NE%4==0 -> tail int4-exact
    if (ok) {
        int4 d4 = *(const int4*)&dst[e0];
        int4 s4 = *(const int4*)&src[e0];
        b0 = d4.x / PART; k0 = ((unsigned int)(d4.x - b0 * PART) << 17) | (unsigned int)s4.x;
        b1 = d4.y / PART; k1 = ((unsigned int)(d4.y - b1 * PART) << 17) | (unsigned int)s4.y;
        b2 = d4.z / PART; k2 = ((unsigned int)(d4.z - b2 * PART) << 17) | (unsigned int)s4.z;
        b3 = d4.w / PART; k3 = ((unsigned int)(d4.w - b3 * PART) << 17) | (unsigned int)s4.w;
        p0 = atomicAdd(&hist[b0], 1);
        p1 = atomicAdd(&hist[b1], 1);
        p2 = atomicAdd(&hist[b2], 1);
        p3 = atomicAdd(&hist[b3], 1);
    }
    __syncthreads();
    base[tid] = atomicAdd(&bucketCnt[tid], hist[tid]);
    __syncthreads();
    if (ok) {
        staging[b0 * CAP + base[b0] + p0] = k0;
        staging[b1 * CAP + base[b1] + p1] = k1;
        staging[b2 * CAP + base[b2] + p2] = k2;
        staging[b3 * CAP + base[b3] + p3] = k3;
    }
}

// ---- Phase 2: degree count. Block b sweeps ONLY its ~6250-entry bucket.
__global__ __launch_bounds__(256)
void count_kernel(const unsigned int* __restrict__ staging,
                  const int* __restrict__ bucketCnt, int* __restrict__ deg) {
    __shared__ int hist[PART];
    int b = blockIdx.x;
    int tid = threadIdx.x;
    for (int i = tid; i < PART; i += 256) hist[i] = 0;
    __syncthreads();
    int cnt = bucketCnt[b];
    const unsigned int* st = staging + b * CAP;
    for (int i = tid; i < cnt; i += 256) atomicAdd(&hist[st[i] >> 17], 1);
    __syncthreads();
    int dbase = b * PART;
    for (int i = tid; i < PART; i += 256)
        if (dbase + i < NN) deg[dbase + i] = hist[i];
}

__global__ void scan1_kernel(const int* __restrict__ deg, int* __restrict__ loc,
                             int* __restrict__ bsum) {
    int t = threadIdx.x;
    int i = blockIdx.x * 1024 + t;
    int v = (i < NN) ? deg[i] : 0;
    __shared__ int ps[1024];
    ps[t] = v;
    __syncthreads();
    #pragma unroll
    for (int off = 1; off < 1024; off <<= 1) {
        int u = (t >= off) ? ps[t - off] : 0;
        __syncthreads();
        ps[t] += u;
        __syncthreads();
    }
    if (i < NN) loc[i] = ps[t] - v;
    if (t == 1023) bsum[blockIdx.x] = ps[1023];
}

__global__ void scan2_kernel(const int* __restrict__ bsum, int* __restrict__ boff) {
    int t = threadIdx.x;                      // 128 threads, 98 valid
    int v = (t < 98) ? bsum[t] : 0;
    __shared__ int ps[128];
    ps[t] = v;
    __syncthreads();
    #pragma unroll
    for (int off = 1; off < 128; off <<= 1) {
        int u = (t >= off) ? ps[t - off] : 0;
        __syncthreads();
        ps[t] += u;
        __syncthreads();
    }
    if (t < 98) boff[t] = ps[t] - v;
    if (t == 127) boff[98] = ps[127];
}

__global__ void scan3_kernel(const int* __restrict__ loc, const int* __restrict__ boff,
                             int* __restrict__ rs) {
    int i = blockIdx.x * 1024 + threadIdx.x;
    if (i < NN) rs[i] = loc[i] + boff[i >> 10];
    if (i == NN) rs[NN] = boff[98];
}

// ---- Phase 3: CSR place. Block b sweeps only its own bucket; single-writer csr region.
__global__ __launch_bounds__(256)
void place_kernel(const unsigned int* __restrict__ staging,
                  const int* __restrict__ bucketCnt, const int* __restrict__ rs,
                  int* __restrict__ csr) {
    __shared__ int cnt[PART];
    int b = blockIdx.x;
    int tid = threadIdx.x;
    for (int i = tid; i < PART; i += 256) cnt[i] = 0;
    __syncthreads();
    int n = bucketCnt[b];
    const unsigned int* st = staging + b * CAP;
    int dbase = b * PART;
    for (int i = tid; i < n; i += 256) {
        unsigned int v = st[i];
        int dloc = (int)(v >> 17);
        int slot = rs[dbase + dloc] + atomicAdd(&cnt[dloc], 1);
        csr[slot] = (int)(v & 0x1FFFFu);
    }
}

// t0 = bf16(x * deg^{-1/2}); last 16 blocks zero pooled (deg/bucketCnt dead here).
// sums is NOT zeroed here — it lives inside tping, which layer 1 overwrites
// (round-16 lesson); it is memset just before mlp1.
__global__ void t0_kernel(const float* __restrict__ x, const int* __restrict__ rs,
                          unsigned short* __restrict__ t0, float* __restrict__ pooled) {
    int nb = gridDim.x - 16;
    if ((int)blockIdx.x >= nb) {
        int z = (blockIdx.x - nb) * 256 + threadIdx.x;   // 4096 threads
        #pragma unroll
        for (int i = 0; i < 32; ++i) pooled[z + i * 4096] = 0.f;  // 131072 floats
        return;
    }
    int i = blockIdx.x * 256 + threadIdx.x;   // over NN*16 quads
    int n = i >> 4;
    float di = rsqrtf((float)(rs[n + 1] - rs[n]) + 1.0f);
    float4 v = ((const float4*)x)[i];
    ushort4 o;
    o.x = f2bf(v.x * di); o.y = f2bf(v.y * di);
    o.z = f2bf(v.z * di); o.w = f2bf(v.w * di);
    ((ushort4*)t0)[i] = o;
}

// Gather ONLY: v[n] = bf16( dis[n] * (t[n] + sum_nbr t[src]) ).
// Quarter-wave per node; 8 rows in flight per quarter-wave — the measured
// optimum (round-17 A/B: 16-deep = 50.0 µs @51% occ vs 8-deep = 47.5 µs @67%;
// gather is fabric-BW-bound at ~3.5 TB/s, deeper ILP only costs occupancy).
__global__ __launch_bounds__(256)
void gather_kernel(const unsigned short* __restrict__ t, const int* __restrict__ csr,
                   const int* __restrict__ rs, unsigned short* __restrict__ vout) {
    const uint2* tu2 = (const uint2*)t;
    uint2* vo2 = (uint2*)vout;
    int tid = threadIdx.x;
    // bijective XCD chunk-swizzle
    int nwg = gridDim.x;                 // 6250
    int q = nwg >> 3, r = nwg & 7;       // 781, 2
    int xcd = blockIdx.x & 7, sub = blockIdx.x >> 3;
    int bid = (xcd < r ? xcd * (q + 1) : r * (q + 1) + (xcd - r) * q) + sub;

    int n = bid * 16 + (tid >> 4);       // quarter-wave -> node
    int l = tid & 15;                    // uint2 index: channels 4l..4l+3
    int j0 = rs[n], j1 = rs[n + 1];
    float di = rsqrtf((float)(j1 - j0) + 1.0f);

    uint2 sv = tu2[n * 16 + l];          // self row
    float a0 = plo(sv.x), a1 = phi(sv.x), a2 = plo(sv.y), a3 = phi(sv.y);

    int j = j0;
    #pragma clang loop unroll(disable)
    for (; j + 7 < j1; j += 8) {         // 8 rows in flight per quarter
        int i0 = csr[j],     i1 = csr[j + 1], i2 = csr[j + 2], i3 = csr[j + 3];
        int i4 = csr[j + 4], i5 = csr[j + 5], i6 = csr[j + 6], i7 = csr[j + 7];
        uint2 v0 = tu2[i0 * 16 + l];
        uint2 v1 = tu2[i1 * 16 + l];
        uint2 v2 = tu2[i2 * 16 + l];
        uint2 v3 = tu2[i3 * 16 + l];
        uint2 v4 = tu2[i4 * 16 + l];
        uint2 v5 = tu2[i5 * 16 + l];
        uint2 v6 = tu2[i6 * 16 + l];
        uint2 v7 = tu2[i7 * 16 + l];
        a0 += ((plo(v0.x) + plo(v1.x)) + (plo(v2.x) + plo(v3.x)))
            + ((plo(v4.x) + plo(v5.x)) + (plo(v6.x) + plo(v7.x)));
        a1 += ((phi(v0.x) + phi(v1.x)) + (phi(v2.x) + phi(v3.x)))
            + ((phi(v4.x) + phi(v5.x)) + (phi(v6.x) + phi(v7.x)));
        a2 += ((plo(v0.y) + plo(v1.y)) + (plo(v2.y) + plo(v3.y)))
            + ((plo(v4.y) + plo(v5.y)) + (plo(v6.y) + plo(v7.y)));
        a3 += ((phi(v0.y) + phi(v1.y)) + (phi(v2.y) + phi(v3.y)))
            + ((phi(v4.y) + phi(v5.y)) + (phi(v6.y) + phi(v7.y)));
    }
    #pragma clang loop unroll(disable)
    for (; j + 3 < j1; j += 4) {
        int i0 = csr[j], i1 = csr[j + 1], i2 = csr[j + 2], i3 = csr[j + 3];
        uint2 v0 = tu2[i0 * 16 + l];
        uint2 v1 = tu2[i1 * 16 + l];
        uint2 v2 = tu2[i2 * 16 + l];
        uint2 v3 = tu2[i3 * 16 + l];
        a0 += (plo(v0.x) + plo(v1.x)) + (plo(v2.x) + plo(v3.x));
        a1 += (phi(v0.x) + phi(v1.x)) + (phi(v2.x) + phi(v3.x));
        a2 += (plo(v0.y) + plo(v1.y)) + (plo(v2.y) + plo(v3.y));
        a3 += (phi(v0.y) + phi(v1.y)) + (phi(v2.y) + phi(v3.y));
    }
    #pragma clang loop unroll(disable)
    for (; j < j1; ++j) {
        uint2 v0 = tu2[csr[j] * 16 + l];
        a0 += plo(v0.x); a1 += phi(v0.x);
        a2 += plo(v0.y); a3 += phi(v0.y);
    }
    uint2 o;
    o.x = (unsigned int)f2bf(a0 * di) | ((unsigned int)f2bf(a1 * di) << 16);
    o.y = (unsigned int)f2bf(a2 * di) | ((unsigned int)f2bf(a3 * di) << 16);
    vo2[n * 16 + l] = o;
}

// Persistent-W grid-stride GEMM + epilogue: h = v @ W + b; tout = bf16(dis*h);
// pooled[batch] += h with LDS cross-wave reduction.
__global__ __launch_bounds__(256)
void vgemm_kernel(const unsigned short* __restrict__ v, const float* __restrict__ W,
                  const float* __restrict__ bias, const int* __restrict__ rs,
                  const int* __restrict__ batch, unsigned short* __restrict__ tout,
                  float* __restrict__ pooled, int l, int last) {
    __shared__ float Wsh[64 * 64];
    __shared__ float hs[16][64];
    __shared__ float red[4][64];
    const uint2* vu2 = (const uint2*)v;
    int tid = threadIdx.x;
    #pragma unroll
    for (int i = 0; i < 16; ++i) Wsh[tid + i * 256] = W[tid + i * 256];  // once/block
    int w = tid >> 6, d = tid & 63;
    float bd = bias[d];

    for (int c = blockIdx.x; c < NN / 16; c += gridDim.x) {
        int n0 = c * 16;
        {
            int rr = tid >> 4, cc = tid & 15;    // one uint2/thread = 4 channels
            uint2 u = vu2[(n0 + rr) * 16 + cc];
            hs[rr][4 * cc]     = plo(u.x);
            hs[rr][4 * cc + 1] = phi(u.x);
            hs[rr][4 * cc + 2] = plo(u.y);
            hs[rr][4 * cc + 3] = phi(u.y);
        }
        __syncthreads();
        float a0 = 0.f, a1 = 0.f, a2 = 0.f, a3 = 0.f;
        #pragma unroll 2
        for (int k4 = 0; k4 < 16; ++k4) {        // 4 b128 + 4 b32 LDS per 16 FMA
            float4 h0 = *(const float4*)&hs[w * 4 + 0][k4 * 4];
            float4 h1 = *(const float4*)&hs[w * 4 + 1][k4 * 4];
            float4 h2 = *(const float4*)&hs[w * 4 + 2][k4 * 4];
            float4 h3 = *(const float4*)&hs[w * 4 + 3][k4 * 4];
            float w0 = Wsh[(k4 * 4 + 0) * 64 + d];
            float w1 = Wsh[(k4 * 4 + 1) * 64 + d];
            float w2 = Wsh[(k4 * 4 + 2) * 64 + d];
            float w3 = Wsh[(k4 * 4 + 3) * 64 + d];
            a0 = fmaf(h0.x, w0, a0); a0 = fmaf(h0.y, w1, a0);
            a0 = fmaf(h0.z, w2, a0); a0 = fmaf(h0.w, w3, a0);
            a1 = fmaf(h1.x, w0, a1); a1 = fmaf(h1.y, w1, a1);
            a1 = fmaf(h1.z, w2, a1); a1 = fmaf(h1.w, w3, a1);
            a2 = fmaf(h2.x, w0, a2); a2 = fmaf(h2.y, w1, a2);
            a2 = fmaf(h2.z, w2, a2); a2 = fmaf(h2.w, w3, a2);
            a3 = fmaf(h3.x, w0, a3); a3 = fmaf(h3.y, w1, a3);
            a3 = fmaf(h3.z, w2, a3); a3 = fmaf(h3.w, w3, a3);
        }
        float accs[4] = {a0, a1, a2, a3};
        if (!last) {
            #pragma unroll
            for (int s = 0; s < 4; ++s) {
                int n = n0 + w * 4 + s;
                float di = rsqrtf((float)(rs[n + 1] - rs[n]) + 1.0f);
                tout[n * 64 + d] = f2bf((accs[s] + bd) * di);
            }
        }
        int glo = batch[n0], ghi = batch[n0 + 15];
        if (glo == ghi) {                         // block-uniform branch
            red[w][d] = ((a0 + a1) + (a2 + a3)) + 4.0f * bd;
            __syncthreads();
            if (w == 0) {
                float tot = (red[0][d] + red[1][d]) + (red[2][d] + red[3][d]);
                atomicAdd(&pooled[glo * 256 + l * 64 + d], tot);
            }
        } else {
            #pragma unroll
            for (int s = 0; s < 4; ++s) {
                int n = n0 + w * 4 + s;
                atomicAdd(&pooled[batch[n] * 256 + l * 64 + d], accs[s] + bd);
            }
        }
        __syncthreads();                          // hs/red reuse barrier
    }
}

__global__ void mlp1_kernel(const float* __restrict__ pooled, const float* __restrict__ W1,
                            const float* __restrict__ b1, float* __restrict__ z1,
                            float* __restrict__ sums) {
    __shared__ float row[256];
    int g = blockIdx.x, d = threadIdx.x;   // 64 threads
    #pragma unroll
    for (int i = 0; i < 4; ++i) row[d + i * 64] = pooled[g * 256 + d + i * 64];
    __syncthreads();
    float acc = b1[d];
    #pragma unroll 8
    for (int k = 0; k < 256; ++k) acc = fmaf(row[k], W1[k * 64 + d], acc);
    z1[g * 64 + d] = acc;
    atomicAdd(&sums[d], acc);
    atomicAdd(&sums[64 + d], acc * acc);
}

__global__ void mlp2_kernel(const float* __restrict__ z1, const float* __restrict__ sums,
                            const float* __restrict__ gamma, const float* __restrict__ beta,
                            const float* __restrict__ W2, const float* __restrict__ b2,
                            float* __restrict__ out) {
    int g = blockIdx.x, d = threadIdx.x;   // 64 threads = 1 wave
    float mean = sums[d] * (1.0f / 512.0f);
    float var  = sums[64 + d] * (1.0f / 512.0f) - mean * mean;
    float z = (z1[g * 64 + d] - mean) * rsqrtf(var + EPSV) * gamma[d] + beta[d];
    z = fmaxf(z, 0.0f);
    #pragma unroll
    for (int o = 0; o < OUTC; ++o) {
        float v = z * W2[d * OUTC + o];
        #pragma unroll
        for (int s = 32; s; s >>= 1) v += __shfl_xor(v, s, 64);
        if (d == 0) out[g * OUTC + o] = v + b2[o];
    }
}

extern "C" void kernel_launch(void* const* d_in, const int* in_sizes, int n_in,
                              void* d_out, int out_size, void* d_ws, size_t ws_size,
                              hipStream_t stream) {
    (void)in_sizes; (void)n_in; (void)out_size; (void)ws_size;
    const float* x     = (const float*)d_in[0];
    const int*   ei    = (const int*)d_in[1];
    const int*   src   = ei;
    const int*   dst   = ei + NE;
    const int*   batch = (const int*)d_in[2];
    const float* Wc    = (const float*)d_in[3];
    const float* bc    = (const float*)d_in[4];
    const float* W1    = (const float*)d_in[5];
    const float* b1    = (const float*)d_in[6];
    const float* gamma = (const float*)d_in[7];
    const float* beta  = (const float*)d_in[8];
    const float* W2    = (const float*)d_in[9];
    const float* b2    = (const float*)d_in[10];
    float* out = (float*)d_out;
    float* ws  = (float*)d_ws;

    int*   rs        = (int*)(ws + OFF_RS);
    int*   csr       = (int*)(ws + OFF_CSR);
    int*   loc       = (int*)(ws + OFF_CSR);        // scan temp, dead before place
    unsigned short* tping = (unsigned short*)(ws + OFF_BUFA);
    unsigned short* vbuf  = tping + 6400000;        // second half of BUFA region
    unsigned short* tpong = (unsigned short*)(ws + OFF_BUFB);
    unsigned int* staging = (unsigned int*)(ws + OFF_BUFB);  // 8 MB, dead before layers
    float* pooled = ws + OFF_POOL;
    int*   deg       = (int*)(ws + OFF_POOL);       // dead before t0's pooled-zero
    int*   bucketCnt = (int*)(ws + OFF_POOL) + NN;  // 256 ints, same overlay
    int*   bsum   = (int*)(ws + OFF_BUFA);          // scan temps, dead before t0
    int*   boff   = (int*)(ws + OFF_BUFA) + 128;
    float* z1     = ws + OFF_BUFA;                  // overlay, dead only AFTER layers
    float* sums   = ws + OFF_BUFA + GG * DD;        // inside tping -> zero AFTER layers

    // --- build CSR: bucket (1 sweep, 256-way) -> own-bucket count -> scan -> place ---
    hipMemsetAsync(bucketCnt, 0, 256 * sizeof(int), stream);
    bucket_kernel<<<(NE + 1023) / 1024, 256, 0, stream>>>(src, dst, bucketCnt, staging);
    count_kernel<<<256, 256, 0, stream>>>(staging, bucketCnt, deg);
    scan1_kernel<<<98, 1024, 0, stream>>>(deg, loc, bsum);
    scan2_kernel<<<1, 128, 0, stream>>>(bsum, boff);
    scan3_kernel<<<99, 1024, 0, stream>>>(loc, boff, rs);
    place_kernel<<<256, 256, 0, stream>>>(staging, bucketCnt, rs, csr);

    // --- t0 = bf16(x * dis); fused pooled zeroing (deg/bucketCnt dead now) ---
    t0_kernel<<<NN * 16 / 256 + 16, 256, 0, stream>>>(x, rs, tping, pooled);

    // --- layers: gather (fabric-BW floor) then persistent-W GEMM ---
    unsigned short* tin = tping; unsigned short* tot = tpong;
    for (int l = 0; l < LL; ++l) {
        gather_kernel<<<NN / 16, 256, 0, stream>>>(tin, csr, rs, vbuf);
        vgemm_kernel<<<768, 256, 0, stream>>>(vbuf, Wc + l * 4096, bc + l * 64,
                                              rs, batch, tot, pooled,
                                              l, l == LL - 1);
        unsigned short* tmp = tin; tin = tot; tot = tmp;
    }

    // --- MLP head: sums zeroed HERE (after all tping writes — round-16 lesson) ---
    hipMemsetAsync(sums, 0, 128 * sizeof(float), stream);
    mlp1_kernel<<<GG, 64, 0, stream>>>(pooled, W1, b1, z1, sums);
    mlp2_kernel<<<GG, 64, 0, stream>>>(z1, sums, gamma, beta, W2, b2, out);
}